// Round 7
// baseline (331.788 us; speedup 1.0000x reference)
//
#include <hip/hip_runtime.h>
#include <hip/hip_bf16.h>

#define B_   2
#define S_   2048
#define H_   1024
#define NH_  16
#define DH_  64

typedef __attribute__((ext_vector_type(8))) __bf16 bf16x8;
typedef __attribute__((ext_vector_type(8))) unsigned short u16x8;
typedef __attribute__((ext_vector_type(4))) float f32x4;

typedef const __attribute__((address_space(1))) unsigned int gu32_t;
typedef __attribute__((address_space(3))) unsigned int su32_t;

static __device__ inline unsigned short f2bf(float x) {
    union { float f; unsigned u; } v; v.f = x;
    unsigned r = v.u + 0x7fffu + ((v.u >> 16) & 1u);
    return (unsigned short)(r >> 16);
}

// fast round-half-up bf16 (2 VALU ops); used for P in [0, ~20] — symmetric +/-2^-9 rel err
static __device__ inline unsigned short f2bf_r(float x) {
    union { float f; unsigned u; } v; v.f = x;
    return (unsigned short)((v.u + 0x8000u) >> 16);
}

static __device__ inline bf16x8 ldfrag(const unsigned short* p) {
    return __builtin_bit_cast(bf16x8, *(const u16x8*)p);
}

// ---------------- fused conversions: hidden->bf16, W->packed bf16, demb->transposed f32 ----------------
// demb table is now TRANSPOSED TO F32 [16][4096] in global (256 KB, L2-resident): attn
// gathers it with scattered global loads instead of LDS gathers (moves the dominant
// LDS-pipe term + all its bank conflicts onto the underused VMEM path).
__global__ void conv_all(const float* __restrict__ x,
                         const float* __restrict__ Wq, const float* __restrict__ Wk,
                         const float* __restrict__ Wv, const float* __restrict__ demb,
                         unsigned short* __restrict__ xb, unsigned short* __restrict__ wall,
                         float* __restrict__ dembTf) {
    int bid = blockIdx.x, tid = threadIdx.x;
    if (bid < 4096) {
        int i = bid * 256 + tid;                 // float4 index, 1M total
        float4 v = ((const float4*)x)[i];
        ushort4 o;
        o.x = f2bf(v.x); o.y = f2bf(v.y); o.z = f2bf(v.z); o.w = f2bf(v.w);
        ((ushort4*)xb)[i] = o;
    } else if (bid < 7168) {
        int i = (bid - 4096) * 256 + tid;        // float4 index, 768K total
        int e = i * 4;
        int which = e >> 20;                      // H*H = 1<<20 per matrix
        int r4 = (e & ((1 << 20) - 1)) >> 2;
        const float* src = which == 0 ? Wq : which == 1 ? Wk : Wv;
        float4 v = ((const float4*)src)[r4];
        ushort4 o;
        o.x = f2bf(v.x); o.y = f2bf(v.y); o.z = f2bf(v.z); o.w = f2bf(v.w);
        ((ushort4*)wall)[i] = o;
    } else {
        int t = (bid - 7168) * 256 + tid;        // 65536 total
        int h = t >> 12, e = t & 4095;
        dembTf[t] = demb[e * 16 + h];            // plain transpose, keep f32
    }
}

// ---------------- QKV GEMM (m97-style, round-0 verified): [4096,1024] x [3072,1024]^T ----------------
// NOTE: round-6's double-buffer variant regressed ~6us (consistent with m99/m100/m230:
// 2-phase dbuf grafts are neutral-to-negative). Reverted to the verified single-buffer.
__global__ __launch_bounds__(256) void gemm_qkv(
    const unsigned short* __restrict__ Xb, const unsigned short* __restrict__ Wall,
    const float* __restrict__ bq, const float* __restrict__ bk, const float* __restrict__ bv,
    unsigned short* __restrict__ Q, unsigned short* __restrict__ K, unsigned short* __restrict__ V)
{
    __shared__ unsigned short As[128 * 32];
    __shared__ unsigned short Bs[128 * 32];
    const int tid = threadIdx.x, lane = tid & 63, wv = tid >> 6;
    const int g = lane >> 4, l16 = lane & 15;
    const int wm = wv >> 1, wn = wv & 1;
    const int bm = blockIdx.y, bn = blockIdx.x;

    // one wave-instruction = 64 lanes x 16B = 1KB = 16 rows x 32 cols
    const int lrow = lane >> 2, lcol = (lane & 3) * 8;

    f32x4 acc[4][4];
    #pragma unroll
    for (int i = 0; i < 4; ++i)
        #pragma unroll
        for (int j = 0; j < 4; ++j) acc[i][j] = (f32x4){0.f, 0.f, 0.f, 0.f};

    for (int kt = 0; kt < 32; ++kt) {
        #pragma unroll
        for (int i = 0; i < 2; ++i) {
            int chunk = wv * 2 + i;                  // 0..7, each = 16 rows (128 rows total)
            int row = chunk * 16 + lrow;
            const unsigned short* ga = &Xb[(size_t)(bm * 128 + row) * 1024 + kt * 32 + lcol];
            const unsigned short* gb = &Wall[(size_t)(bn * 128 + row) * 1024 + kt * 32 + lcol];
            __builtin_amdgcn_global_load_lds((gu32_t*)(const void*)ga, (su32_t*)(void*)&As[chunk * 512], 16, 0, 0);
            __builtin_amdgcn_global_load_lds((gu32_t*)(const void*)gb, (su32_t*)(void*)&Bs[chunk * 512], 16, 0, 0);
        }
        __syncthreads();
        bf16x8 a[4], b[4];
        #pragma unroll
        for (int mi = 0; mi < 4; ++mi) a[mi] = ldfrag(&As[(wm * 64 + mi * 16 + l16) * 32 + g * 8]);
        #pragma unroll
        for (int ni = 0; ni < 4; ++ni) b[ni] = ldfrag(&Bs[(wn * 64 + ni * 16 + l16) * 32 + g * 8]);
        #pragma unroll
        for (int mi = 0; mi < 4; ++mi)
            #pragma unroll
            for (int ni = 0; ni < 4; ++ni)
                acc[mi][ni] = __builtin_amdgcn_mfma_f32_16x16x32_bf16(a[mi], b[ni], acc[mi][ni], 0, 0, 0);
        __syncthreads();
    }

    // epilogue: D row = g*4+r, col = l16
    #pragma unroll
    for (int mi = 0; mi < 4; ++mi) {
        #pragma unroll
        for (int ni = 0; ni < 4; ++ni) {
            int gn = bn * 128 + wn * 64 + ni * 16 + l16;
            int which = gn >> 10, nn = gn & 1023;
            int h = nn >> 6, d = nn & 63;
            float bias = which == 0 ? bq[nn] : which == 1 ? bk[nn] : bv[nn];
            unsigned short* dst = which == 0 ? Q : which == 1 ? K : V;
            #pragma unroll
            for (int r = 0; r < 4; ++r) {
                int gm = bm * 128 + wm * 64 + mi * 16 + g * 4 + r;
                int bb = gm >> 11, s = gm & 2047;
                dst[((size_t)(bb * 16 + h) * 2048 + s) * 64 + d] = f2bf(acc[mi][ni][r] + bias);
            }
        }
    }
}

// ---------------- V transpose: [b,h,s,d] -> [b,h,d,s] ----------------
__global__ void transpose_v(const unsigned short* __restrict__ V, unsigned short* __restrict__ VT) {
    __shared__ unsigned short t[64][65];
    int bh = blockIdx.y, st = blockIdx.x, tid = threadIdx.x;
    size_t ib = (size_t)bh * S_ * DH_ + (size_t)st * 64 * 64;   // contiguous 64x64 tile
    #pragma unroll
    for (int rep = 0; rep < 16; ++rep) {
        int e = rep * 256 + tid;
        t[e >> 6][e & 63] = V[ib + e];
    }
    __syncthreads();
    size_t ob = (size_t)bh * DH_ * S_ + st * 64;
    #pragma unroll
    for (int rep = 0; rep < 16; ++rep) {
        int e = rep * 256 + tid;
        int d = e >> 6, sl = e & 63;
        VT[ob + (size_t)d * S_ + sl] = t[sl][d];
    }
}

// ---------------- fused flash attention with relative bias ----------------
// Round-0 structure (verified 100.6us) with ONE change: demb gathers moved from LDS
// (16 random ds_read_u16/thread/iter, ~160 LDS-cy + 1.04e7 conflict cycles) to 16
// scattered GLOBAL f32 loads from the L2-resident 256KB table. LDS pipe was the
// bottleneck (joint LDS+VALU model: 424 vs 370 cy/wave-iter); VMEM path is underused.
// LDS: Ks 8KB + Vs 8KB + Ps 8KB = 24KB -> 4 blocks/CU (grid-limited).
__global__ __launch_bounds__(256, 4) void attn(
    const unsigned short* __restrict__ Q, const unsigned short* __restrict__ K,
    const unsigned short* __restrict__ VT, const int* __restrict__ didx,
    const float* __restrict__ demb_f, const float* __restrict__ mask,
    float* __restrict__ out)
{
    __shared__ unsigned short Ks[64 * 64];
    __shared__ unsigned short Vs[64 * 64];
    __shared__ unsigned short Ps[4][16 * 64];
    const int tid = threadIdx.x, lane = tid & 63, w = tid >> 6;
    const int g = lane >> 4, l16 = lane & 15;
    const int h = blockIdx.x, qt = blockIdx.y, b = blockIdx.z;
    const int bh = b * NH_ + h;
    const int qr = qt * 64 + w * 16;

    bf16x8 qf[2];
    {
        size_t qbase = ((size_t)bh * S_ + qr + l16) * DH_;
        qf[0] = ldfrag(&Q[qbase + g * 8]);
        qf[1] = ldfrag(&Q[qbase + 32 + g * 8]);
    }

    f32x4 oa[4];
    float lsum[4];
    #pragma unroll
    for (int i = 0; i < 4; ++i) {
        oa[i] = (f32x4){0.f, 0.f, 0.f, 0.f};
        lsum[i] = 0.f;
    }

    const size_t kbase = (size_t)bh * S_ * DH_;
    const size_t vbase = (size_t)bh * DH_ * S_;
    const float* dh = &demb_f[h * 4096];

    for (int kt = 0; kt < 32; ++kt) {
        #pragma unroll
        for (int j = 0; j < 2; ++j) {
            int e = j * 2048 + tid * 8;
            int r = e >> 6, c = e & 63;
            int sidx = r * 64 + ((((c >> 3) ^ (r & 7))) << 3);
            *(uint4*)&Ks[sidx] = *(const uint4*)&K[kbase + (size_t)kt * 64 * 64 + e];
            *(uint4*)&Vs[sidx] = *(const uint4*)&VT[vbase + (size_t)r * S_ + kt * 64 + c];
        }

        // issue didx early, then the dependent global bias gathers (L2-hot table);
        // both drain at the barrier, hidden by staging + 16 waves/CU of TLP
        int ei[4][4];
        float mk[4];
        #pragma unroll
        for (int kj = 0; kj < 4; ++kj) {
            int kg = kt * 64 + kj * 16 + l16;
            mk[kj] = mask[b * S_ + kg];
            #pragma unroll
            for (int r = 0; r < 4; ++r) {
                int qg = qr + g * 4 + r;
                ei[kj][r] = didx[qg * S_ + kg];
            }
        }
        float df[4][4];
        #pragma unroll
        for (int kj = 0; kj < 4; ++kj)
            #pragma unroll
            for (int r = 0; r < 4; ++r)
                df[kj][r] = dh[ei[kj][r]];

        __syncthreads();

        // QK^T: 4 column tiles of 16 keys
        f32x4 sc[4];
        #pragma unroll
        for (int kj = 0; kj < 4; ++kj) {
            int row = kj * 16 + l16, m = row & 7;
            bf16x8 kf0 = ldfrag(&Ks[row * 64 + ((g ^ m) << 3)]);
            bf16x8 kf1 = ldfrag(&Ks[row * 64 + (((g + 4) ^ m) << 3)]);
            f32x4 z = (f32x4){0.f, 0.f, 0.f, 0.f};
            z = __builtin_amdgcn_mfma_f32_16x16x32_bf16(qf[0], kf0, z, 0, 0, 0);
            z = __builtin_amdgcn_mfma_f32_16x16x32_bf16(qf[1], kf1, z, 0, 0, 0);
            sc[kj] = z;
        }

        // p = exp(score*0.125 + bias + mask); accumulate per-lane row sums
        #pragma unroll
        for (int kj = 0; kj < 4; ++kj) {
            #pragma unroll
            for (int r = 0; r < 4; ++r) {
                float bm = df[kj][r] + mk[kj];
                float p = __expf(fmaf(sc[kj][r], 0.125f, bm));
                lsum[r] += p;
                int row = g * 4 + r;
                int idx = row * 64 + ((((kj * 2 + (l16 >> 3)) ^ (row & 7))) << 3) + (l16 & 7);
                Ps[w][idx] = f2bf_r(p);
            }
        }

        // PV: P (A-layout from LDS) x V — no rescale needed (fixed max)
        int pm = l16 & 7;
        bf16x8 pf0 = ldfrag(&Ps[w][l16 * 64 + ((g ^ pm) << 3)]);
        bf16x8 pf1 = ldfrag(&Ps[w][l16 * 64 + (((g + 4) ^ pm) << 3)]);
        #pragma unroll
        for (int dt = 0; dt < 4; ++dt) {
            int row = dt * 16 + l16, m = row & 7;
            bf16x8 vf0 = ldfrag(&Vs[row * 64 + ((g ^ m) << 3)]);
            bf16x8 vf1 = ldfrag(&Vs[row * 64 + (((g + 4) ^ m) << 3)]);
            oa[dt] = __builtin_amdgcn_mfma_f32_16x16x32_bf16(pf0, vf0, oa[dt], 0, 0, 0);
            oa[dt] = __builtin_amdgcn_mfma_f32_16x16x32_bf16(pf1, vf1, oa[dt], 0, 0, 0);
        }
        __syncthreads();
    }

    // one final 16-lane reduction of the row sums
    float linv[4];
    #pragma unroll
    for (int r = 0; r < 4; ++r) {
        float s = lsum[r];
        s += __shfl_xor(s, 1);
        s += __shfl_xor(s, 2);
        s += __shfl_xor(s, 4);
        s += __shfl_xor(s, 8);
        linv[r] = __builtin_amdgcn_rcpf(s);
    }

    #pragma unroll
    for (int dt = 0; dt < 4; ++dt) {
        #pragma unroll
        for (int r = 0; r < 4; ++r) {
            int s = qr + g * 4 + r;
            int d = dt * 16 + l16;
            out[((size_t)b * S_ + s) * H_ + h * DH_ + d] = oa[dt][r] * linv[r];
        }
    }
}

extern "C" void kernel_launch(void* const* d_in, const int* in_sizes, int n_in,
                              void* d_out, int out_size, void* d_ws, size_t ws_size,
                              hipStream_t stream) {
    const float* hidden = (const float*)d_in[0];
    const float* mask   = (const float*)d_in[1];
    const int*   didx   = (const int*)d_in[2];
    const float* Wq     = (const float*)d_in[3];
    const float* bq     = (const float*)d_in[4];
    const float* Wk     = (const float*)d_in[5];
    const float* bk     = (const float*)d_in[6];
    const float* Wv     = (const float*)d_in[7];
    const float* bv     = (const float*)d_in[8];
    const float* demb   = (const float*)d_in[9];
    float* out = (float*)d_out;

    unsigned short* ws = (unsigned short*)d_ws;
    unsigned short* Xb   = ws;                        // 4096*1024
    unsigned short* Wall = Xb + 4096 * 1024;          // 3072*1024
    unsigned short* Qb   = Wall + 3072 * 1024;        // 4194304 each
    unsigned short* Kb   = Qb + 4194304;
    unsigned short* Vb   = Kb + 4194304;
    unsigned short* VTb  = Vb + 4194304;
    float* DembTf = (float*)(VTb + 4194304);          // 65536 f32 ([16][4096], 256 KB)

    conv_all<<<7424, 256, 0, stream>>>(hidden, Wq, Wk, Wv, demb, Xb, Wall, DembTf);
    gemm_qkv<<<dim3(24, 32), 256, 0, stream>>>(Xb, Wall, bq, bk, bv, Qb, Kb, Vb);
    transpose_v<<<dim3(32, 32), 256, 0, stream>>>(Vb, VTb);
    attn<<<dim3(16, 32, 2), 256, 0, stream>>>(Qb, Kb, VTb, didx, DembTf, mask, out);
}

// Round 8
// 238.686 us; speedup vs baseline: 1.3901x; 1.3901x over previous
//
#include <hip/hip_runtime.h>
#include <hip/hip_bf16.h>

#define B_   2
#define S_   2048
#define H_   1024
#define NH_  16
#define DH_  64

typedef __attribute__((ext_vector_type(8))) __bf16 bf16x8;
typedef __attribute__((ext_vector_type(8))) unsigned short u16x8;
typedef __attribute__((ext_vector_type(4))) float f32x4;
typedef __attribute__((ext_vector_type(4))) short i16x4;

typedef const __attribute__((address_space(1))) unsigned int gu32_t;
typedef __attribute__((address_space(3))) unsigned int su32_t;

static __device__ inline unsigned short f2bf(float x) {
    union { float f; unsigned u; } v; v.f = x;
    unsigned r = v.u + 0x7fffu + ((v.u >> 16) & 1u);
    return (unsigned short)(r >> 16);
}

// fast round-half-up bf16 (2 VALU ops); used for P in [0, ~20] — symmetric +/-2^-9 rel err
static __device__ inline unsigned short f2bf_r(float x) {
    union { float f; unsigned u; } v; v.f = x;
    return (unsigned short)((v.u + 0x8000u) >> 16);
}

static __device__ inline float bf2f(unsigned short u) {
    union { unsigned u; float f; } v; v.u = ((unsigned)u) << 16;
    return v.f;
}

static __device__ inline bf16x8 ldfrag(const unsigned short* p) {
    return __builtin_bit_cast(bf16x8, *(const u16x8*)p);
}

// K=16 bf16 MFMA: device pass has the _1k builtin; host pass has NO amdgcn builtins,
// so give it a parse-only fallback — host never executes kernel bodies. (round-4 lesson)
#if __has_builtin(__builtin_amdgcn_mfma_f32_16x16x16bf16_1k)
#define MFMA16(a, b, c) __builtin_amdgcn_mfma_f32_16x16x16bf16_1k((a), (b), (c), 0, 0, 0)
#else
#define MFMA16(a, b, c) (c)
#endif

// ---------------- fused conversions: hidden->bf16, W->packed bf16, demb->transposed bf16 ----------------
__global__ void conv_all(const float* __restrict__ x,
                         const float* __restrict__ Wq, const float* __restrict__ Wk,
                         const float* __restrict__ Wv, const float* __restrict__ demb,
                         unsigned short* __restrict__ xb, unsigned short* __restrict__ wall,
                         unsigned short* __restrict__ dembT) {
    int bid = blockIdx.x, tid = threadIdx.x;
    if (bid < 4096) {
        int i = bid * 256 + tid;                 // float4 index, 1M total
        float4 v = ((const float4*)x)[i];
        ushort4 o;
        o.x = f2bf(v.x); o.y = f2bf(v.y); o.z = f2bf(v.z); o.w = f2bf(v.w);
        ((ushort4*)xb)[i] = o;
    } else if (bid < 7168) {
        int i = (bid - 4096) * 256 + tid;        // float4 index, 768K total
        int e = i * 4;
        int which = e >> 20;                      // H*H = 1<<20 per matrix
        int r4 = (e & ((1 << 20) - 1)) >> 2;
        const float* src = which == 0 ? Wq : which == 1 ? Wk : Wv;
        float4 v = ((const float4*)src)[r4];
        ushort4 o;
        o.x = f2bf(v.x); o.y = f2bf(v.y); o.z = f2bf(v.z); o.w = f2bf(v.w);
        ((ushort4*)wall)[i] = o;
    } else {
        int t = (bid - 7168) * 256 + tid;        // 65536 total
        int h = t >> 12, e = t & 4095;
        dembT[t] = f2bf(demb[e * 16 + h]);
    }
}

// ---------------- QKV GEMM (m97-style, round-0 verified): [4096,1024] x [3072,1024]^T ----------------
__global__ __launch_bounds__(256) void gemm_qkv(
    const unsigned short* __restrict__ Xb, const unsigned short* __restrict__ Wall,
    const float* __restrict__ bq, const float* __restrict__ bk, const float* __restrict__ bv,
    unsigned short* __restrict__ Q, unsigned short* __restrict__ K, unsigned short* __restrict__ V)
{
    __shared__ unsigned short As[128 * 32];
    __shared__ unsigned short Bs[128 * 32];
    const int tid = threadIdx.x, lane = tid & 63, wv = tid >> 6;
    const int g = lane >> 4, l16 = lane & 15;
    const int wm = wv >> 1, wn = wv & 1;
    const int bm = blockIdx.y, bn = blockIdx.x;

    // one wave-instruction = 64 lanes x 16B = 1KB = 16 rows x 32 cols
    const int lrow = lane >> 2, lcol = (lane & 3) * 8;

    f32x4 acc[4][4];
    #pragma unroll
    for (int i = 0; i < 4; ++i)
        #pragma unroll
        for (int j = 0; j < 4; ++j) acc[i][j] = (f32x4){0.f, 0.f, 0.f, 0.f};

    for (int kt = 0; kt < 32; ++kt) {
        #pragma unroll
        for (int i = 0; i < 2; ++i) {
            int chunk = wv * 2 + i;                  // 0..7, each = 16 rows (128 rows total)
            int row = chunk * 16 + lrow;
            const unsigned short* ga = &Xb[(size_t)(bm * 128 + row) * 1024 + kt * 32 + lcol];
            const unsigned short* gb = &Wall[(size_t)(bn * 128 + row) * 1024 + kt * 32 + lcol];
            __builtin_amdgcn_global_load_lds((gu32_t*)(const void*)ga, (su32_t*)(void*)&As[chunk * 512], 16, 0, 0);
            __builtin_amdgcn_global_load_lds((gu32_t*)(const void*)gb, (su32_t*)(void*)&Bs[chunk * 512], 16, 0, 0);
        }
        __syncthreads();
        bf16x8 a[4], b[4];
        #pragma unroll
        for (int mi = 0; mi < 4; ++mi) a[mi] = ldfrag(&As[(wm * 64 + mi * 16 + l16) * 32 + g * 8]);
        #pragma unroll
        for (int ni = 0; ni < 4; ++ni) b[ni] = ldfrag(&Bs[(wn * 64 + ni * 16 + l16) * 32 + g * 8]);
        #pragma unroll
        for (int mi = 0; mi < 4; ++mi)
            #pragma unroll
            for (int ni = 0; ni < 4; ++ni)
                acc[mi][ni] = __builtin_amdgcn_mfma_f32_16x16x32_bf16(a[mi], b[ni], acc[mi][ni], 0, 0, 0);
        __syncthreads();
    }

    // epilogue: D row = g*4+r, col = l16
    #pragma unroll
    for (int mi = 0; mi < 4; ++mi) {
        #pragma unroll
        for (int ni = 0; ni < 4; ++ni) {
            int gn = bn * 128 + wn * 64 + ni * 16 + l16;
            int which = gn >> 10, nn = gn & 1023;
            int h = nn >> 6, d = nn & 63;
            float bias = which == 0 ? bq[nn] : which == 1 ? bk[nn] : bv[nn];
            unsigned short* dst = which == 0 ? Q : which == 1 ? K : V;
            #pragma unroll
            for (int r = 0; r < 4; ++r) {
                int gm = bm * 128 + wm * 64 + mi * 16 + g * 4 + r;
                int bb = gm >> 11, s = gm & 2047;
                dst[((size_t)(bb * 16 + h) * 2048 + s) * 64 + d] = f2bf(acc[mi][ni][r] + bias);
            }
        }
    }
}

// ---------------- V transpose: [b,h,s,d] -> [b,h,d,s] ----------------
__global__ void transpose_v(const unsigned short* __restrict__ V, unsigned short* __restrict__ VT) {
    __shared__ unsigned short t[64][65];
    int bh = blockIdx.y, st = blockIdx.x, tid = threadIdx.x;
    size_t ib = (size_t)bh * S_ * DH_ + (size_t)st * 64 * 64;   // contiguous 64x64 tile
    #pragma unroll
    for (int rep = 0; rep < 16; ++rep) {
        int e = rep * 256 + tid;
        t[e >> 6][e & 63] = V[ib + e];
    }
    __syncthreads();
    size_t ob = (size_t)bh * DH_ * S_ + st * 64;
    #pragma unroll
    for (int rep = 0; rep < 16; ++rep) {
        int e = rep * 256 + tid;
        int d = e >> 6, sl = e & 63;
        VT[ob + (size_t)d * S_ + sl] = t[sl][d];
    }
}

// ---------------- fused flash attention with relative bias ----------------
// LDS-unit-bound (per-CU model: ~1630 LDS-cy/block-iter x 4 blocks x 32 iters = 87us
// = measured; r7 proved gathers = 100% of conflicts and VMEM-scatter is 2x worse).
// This version removes the Ps LDS round-trip (~224 cy/block-iter) while KEEPING
// round-0's q-split occupancy: QK^T computed SWAPPED (mfma(A=kf,B=qf)) so the score
// C-frag [col=l16=q, row=g*4+r=key] lands in-lane as the K=16 PV A-fragment
// (round-5 proved this algebra end-to-end; its failure was occupancy, not layout).
// Each wave owns 16 q-rows, all 64 keys: oa[4] only (16 regs), no Ps buffer.
// didx loads vectorize to int4 (k is lane-contiguous). LDS: demb 8K + Ks 8K + Vs 8K
// = 24KB -> 4 blocks/CU (grid-limited). Fixed-max softmax as round-0.
__global__ __launch_bounds__(256, 4) void attn(
    const unsigned short* __restrict__ Q, const unsigned short* __restrict__ K,
    const unsigned short* __restrict__ VT, const int* __restrict__ didx,
    const unsigned short* __restrict__ dembT, const float* __restrict__ mask,
    float* __restrict__ out)
{
    __shared__ unsigned short demb_h[4096];
    __shared__ unsigned short Ks[64 * 64];
    __shared__ unsigned short Vs[64 * 64];
    const int tid = threadIdx.x, lane = tid & 63, w = tid >> 6;
    const int g = lane >> 4, l16 = lane & 15;
    const int h = blockIdx.x, qt = blockIdx.y, b = blockIdx.z;
    const int bh = b * NH_ + h;
    const int qr = qt * 64 + w * 16;          // this wave's 16 q rows

    // stage this head's demb column (bf16, contiguous)
    #pragma unroll
    for (int j = 0; j < 2; ++j) {
        int i = j * 256 + tid;
        *(uint4*)&demb_h[i * 8] = *(const uint4*)&dembT[h * 4096 + i * 8];
    }

    // Q as B-fragments: lane l16 = q (col), g*8 = dh chunk — same loads as round-0
    bf16x8 qf[2];
    {
        size_t qbase = ((size_t)bh * S_ + qr + l16) * DH_;
        qf[0] = ldfrag(&Q[qbase + g * 8]);
        qf[1] = ldfrag(&Q[qbase + 32 + g * 8]);
    }

    f32x4 oa[4];               // O rows q = qr + g*4 + r, cols d = dt*16 + l16
    #pragma unroll
    for (int i = 0; i < 4; ++i) oa[i] = (f32x4){0.f, 0.f, 0.f, 0.f};
    float lsum = 0.f;          // per-lane: sum of P[q=qr+l16][keys g*4+j, all kj, all kt]

    const size_t kbase = (size_t)bh * S_ * DH_;
    const size_t vbase = (size_t)bh * DH_ * S_;
    const int qg = qr + l16;   // this lane's q row for score/bias indexing

    __syncthreads();           // demb_h ready

    for (int kt = 0; kt < 32; ++kt) {
        // ---- stage K/V tile (round-0 verbatim; xor-swizzled 8-elem chunks) ----
        #pragma unroll
        for (int j = 0; j < 2; ++j) {
            int e = j * 2048 + tid * 8;
            int r = e >> 6, c = e & 63;
            int sidx = r * 64 + ((((c >> 3) ^ (r & 7))) << 3);
            *(uint4*)&Ks[sidx] = *(const uint4*)&K[kbase + (size_t)kt * 4096 + e];
            *(uint4*)&Vs[sidx] = *(const uint4*)&VT[vbase + (size_t)r * S_ + kt * 64 + c];
        }

        // ---- didx (int4: lane's 4 consecutive keys per kj) + mask (float4), early ----
        int4   di[4];
        float4 mv[4];
        #pragma unroll
        for (int kj = 0; kj < 4; ++kj) {
            int kg = kt * 64 + kj * 16 + g * 4;
            di[kj] = *(const int4*)&didx[qg * S_ + kg];
            mv[kj] = *(const float4*)&mask[b * S_ + kg];
        }
        __syncthreads();       // barrier 1: K/V visible

        // ---- QK^T swapped: sc[kj] = S[key = kj*16+g*4+r][q = l16] ----
        f32x4 sc[4];
        #pragma unroll
        for (int kj = 0; kj < 4; ++kj) {
            int row = kj * 16 + l16, m = row & 7;
            bf16x8 kf0 = ldfrag(&Ks[row * 64 + ((g ^ m) << 3)]);
            bf16x8 kf1 = ldfrag(&Ks[row * 64 + (((g + 4) ^ m) << 3)]);
            f32x4 z = (f32x4){0.f, 0.f, 0.f, 0.f};
            z = __builtin_amdgcn_mfma_f32_16x16x32_bf16(kf0, qf[0], z, 0, 0, 0);
            sc[kj] = __builtin_amdgcn_mfma_f32_16x16x32_bf16(kf1, qf[1], z, 0, 0, 0);
        }

        // ---- exp + in-lane pack to K=16 PV A-frags (no LDS round-trip) ----
        i16x4 pa[4];
        #pragma unroll
        for (int kj = 0; kj < 4; ++kj) {
            float p0 = __expf(fmaf(sc[kj][0], 0.125f, bf2f(demb_h[di[kj].x]) + mv[kj].x));
            float p1 = __expf(fmaf(sc[kj][1], 0.125f, bf2f(demb_h[di[kj].y]) + mv[kj].y));
            float p2 = __expf(fmaf(sc[kj][2], 0.125f, bf2f(demb_h[di[kj].z]) + mv[kj].z));
            float p3 = __expf(fmaf(sc[kj][3], 0.125f, bf2f(demb_h[di[kj].w]) + mv[kj].w));
            lsum += (p0 + p1) + (p2 + p3);
            pa[kj][0] = (short)f2bf_r(p0);
            pa[kj][1] = (short)f2bf_r(p1);
            pa[kj][2] = (short)f2bf_r(p2);
            pa[kj][3] = (short)f2bf_r(p3);
        }

        // ---- PV (K=16): oa[dt] += pa[kj] x V[key-slice kj][d-tile dt] ----
        #pragma unroll
        for (int kj = 0; kj < 4; ++kj) {
            #pragma unroll
            for (int dt = 0; dt < 4; ++dt) {
                int vrow = dt * 16 + l16, vm = vrow & 7;
                int chunkc = kj * 2 + (g >> 1);
                int addr = vrow * 64 + (((chunkc ^ vm)) << 3) + ((g & 1) << 2);
                i16x4 vf = *(const i16x4*)&Vs[addr];
                oa[dt] = MFMA16(pa[kj], vf, oa[dt]);
            }
        }
        __syncthreads();       // barrier 2: Ks/Vs free for next tile
    }

    // ---- denominators: reduce over g (lanes with same l16), then redistribute ----
    lsum += __shfl_xor(lsum, 16);
    lsum += __shfl_xor(lsum, 32);      // all lanes now hold denom(q = qr + l16)
    float linv[4];
    #pragma unroll
    for (int r = 0; r < 4; ++r)
        linv[r] = __builtin_amdgcn_rcpf(__shfl(lsum, g * 4 + r));   // denom(q = qr+g*4+r)

    #pragma unroll
    for (int dt = 0; dt < 4; ++dt) {
        #pragma unroll
        for (int r = 0; r < 4; ++r) {
            int s = qr + g * 4 + r;
            int d = dt * 16 + l16;
            out[((size_t)b * S_ + s) * H_ + h * DH_ + d] = oa[dt][r] * linv[r];
        }
    }
}

extern "C" void kernel_launch(void* const* d_in, const int* in_sizes, int n_in,
                              void* d_out, int out_size, void* d_ws, size_t ws_size,
                              hipStream_t stream) {
    const float* hidden = (const float*)d_in[0];
    const float* mask   = (const float*)d_in[1];
    const int*   didx   = (const int*)d_in[2];
    const float* Wq     = (const float*)d_in[3];
    const float* bq     = (const float*)d_in[4];
    const float* Wk     = (const float*)d_in[5];
    const float* bk     = (const float*)d_in[6];
    const float* Wv     = (const float*)d_in[7];
    const float* bv     = (const float*)d_in[8];
    const float* demb   = (const float*)d_in[9];
    float* out = (float*)d_out;

    unsigned short* ws = (unsigned short*)d_ws;
    unsigned short* Xb   = ws;                        // 4096*1024
    unsigned short* Wall = Xb + 4096 * 1024;          // 3072*1024
    unsigned short* Qb   = Wall + 3072 * 1024;        // 4194304 each
    unsigned short* Kb   = Qb + 4194304;
    unsigned short* Vb   = Kb + 4194304;
    unsigned short* VTb  = Vb + 4194304;
    unsigned short* DembT = VTb + 4194304;            // 65536 (bf16 [16][4096])

    conv_all<<<7424, 256, 0, stream>>>(hidden, Wq, Wk, Wv, demb, Xb, Wall, DembT);
    gemm_qkv<<<dim3(24, 32), 256, 0, stream>>>(Xb, Wall, bq, bk, bv, Qb, Kb, Vb);
    transpose_v<<<dim3(32, 32), 256, 0, stream>>>(Vb, VTb);
    attn<<<dim3(16, 32, 2), 256, 0, stream>>>(Qb, Kb, VTb, didx, DembT, mask, out);
}